// Round 11
// baseline (1808.061 us; speedup 1.0000x reference)
//
#include <hip/hip_runtime.h>
#include <math.h>

typedef unsigned short u16;
typedef __attribute__((ext_vector_type(8))) short bf16x8;
typedef __attribute__((ext_vector_type(4))) float f32x4;

// Problem constants
constexpr int cV = 32000, cE = 768, cL = 4, cC = 256, cTL = 1024;
constexpr int cED = 3072, cPIN = 2304;
constexpr int cB = 2, cT = 2048, cN = 8, cNCH = 16, cMR = 16384;

// ---------------------------------------------------------------- bf16 helpers
__device__ inline float bf2f(u16 u) {
    union { uint32_t i; float f; } v; v.i = ((uint32_t)u) << 16; return v.f;
}
__device__ inline u16 f2bf(float f) {
    union { float f; uint32_t u; } v; v.f = f;
    uint32_t r = v.u + 0x7FFF + ((v.u >> 16) & 1);
    return (u16)(r >> 16);
}

// async global->LDS, 16B per lane; LDS dest is wave-uniform base + lane*16
#define GLOAD16(gp, lp) __builtin_amdgcn_global_load_lds( \
    (const __attribute__((address_space(1))) void*)(gp), \
    (__attribute__((address_space(3))) void*)(lp), 16, 0, 0)

#define BARRIER() asm volatile("s_barrier" ::: "memory")

// ---------------------------------------------------------------- reductions
__device__ inline float blockReduceSum256(float v, float* sbuf) {
    #pragma unroll
    for (int m = 1; m < 64; m <<= 1) v += __shfl_xor(v, m, 64);
    int lane = threadIdx.x & 63, w = threadIdx.x >> 6;
    if (lane == 0) sbuf[w] = v;
    __syncthreads();
    return sbuf[0] + sbuf[1] + sbuf[2] + sbuf[3];
}

// ---------------------------------------------------------------- fp32 -> bf16 bulk convert (3 arrays, 1 launch)
__global__ __launch_bounds__(256) void cvt3_k(const float* __restrict__ s0, u16* __restrict__ d0, long n0,
                                              const float* __restrict__ s1, u16* __restrict__ d1, long n1,
                                              const float* __restrict__ s2, u16* __restrict__ d2, long n2) {
    long i = ((long)blockIdx.x * 256 + threadIdx.x) * 4;
    const float* s; u16* d; long off;
    if (i < n0)           { s = s0; d = d0; off = i; }
    else if (i < n0 + n1) { s = s1; d = d1; off = i - n0; }
    else if (i < n0 + n1 + n2) { s = s2; d = d2; off = i - n0 - n1; }
    else return;
    float4 v = *(const float4*)(s + off);
    uint32_t lo = f2bf(v.x) | ((uint32_t)f2bf(v.y) << 16);
    uint32_t hi = f2bf(v.z) | ((uint32_t)f2bf(v.w) << 16);
    *(uint2*)(d + off) = make_uint2(lo, hi);
}

// ---------------------------------------------------------------- embed + token-normalize (fp32, feeds topk)
__global__ __launch_bounds__(256) void embed_k(const int* __restrict__ ids,
                                               const float* __restrict__ wte,
                                               float* __restrict__ x,
                                               float* __restrict__ xnt) {
    __shared__ float sb[4];
    int tok = blockIdx.x;
    const float* src = wte + (size_t)ids[tok] * cE;
    int t = threadIdx.x;
    float v0 = src[t], v1 = src[t + 256], v2 = src[t + 512];
    float tot = blockReduceSum256(v0 * v0 + v1 * v1 + v2 * v2, sb);
    float inv = 1.0f / (sqrtf(tot) + 1e-8f);
    size_t o = (size_t)tok * cE + t;
    x[o] = v0; x[o + 256] = v1; x[o + 512] = v2;
    xnt[o] = v0 * inv; xnt[o + 256] = v1 * inv; xnt[o + 512] = v2 * inv;
}

// ---------------------------------------------------------------- rmsnorm -> bf16
__global__ __launch_bounds__(256) void rmsnorm_bf_k(const float* __restrict__ in,
                                                    const float* __restrict__ w,
                                                    u16* __restrict__ out) {
    __shared__ float sb[4];
    size_t row = blockIdx.x;
    const float* src = in + row * cE;
    int t = threadIdx.x;
    float v0 = src[t], v1 = src[t + 256], v2 = src[t + 512];
    float tot = blockReduceSum256(v0 * v0 + v1 * v1 + v2 * v2, sb);
    float s = 1.0f / sqrtf(tot * (1.0f / cE) + 1e-10f);
    out[row * cE + t]       = f2bf(v0 * s * w[t]);
    out[row * cE + t + 256] = f2bf(v1 * s * w[t + 256]);
    out[row * cE + t + 512] = f2bf(v2 * s * w[t + 512]);
}

// ---------------------------------------------------------------- inverse row norm of a (bf16 input)
__global__ __launch_bounds__(256) void invna_bf_k(const u16* __restrict__ a,
                                                  float* __restrict__ invna) {
    __shared__ float sb[4];
    size_t row = blockIdx.x;
    const u16* src = a + row * cE;
    int t = threadIdx.x;
    float v0 = bf2f(src[t]), v1 = bf2f(src[t + 256]), v2 = bf2f(src[t + 512]);
    float tot = blockReduceSum256(v0 * v0 + v1 * v1 + v2 * v2, sb);
    if (t == 0) invna[row] = 1.0f / sqrtf(tot + 1e-8f);
}

// ---------------------------------------------------------------- final row extract + rmsnorm(lnf) -> bf16
__global__ __launch_bounds__(256) void final_bf_k(const float* __restrict__ h,
                                                  const float* __restrict__ lnf,
                                                  u16* __restrict__ finn) {
    __shared__ float sb[4];
    int tok = blockIdx.x;
    int b = tok >> 11, tt = tok & 2047;
    int i = tt >> 8, c = tt & 255;
    size_t row = (size_t)(b * cN + i) * cTL + (cTL - cC) + c;
    const float* src = h + row * cE;
    int t = threadIdx.x;
    float v0 = src[t], v1 = src[t + 256], v2 = src[t + 512];
    float tot = blockReduceSum256(v0 * v0 + v1 * v1 + v2 * v2, sb);
    float s = 1.0f / sqrtf(tot * (1.0f / cE) + 1e-10f);
    size_t o = (size_t)tok * cE + t;
    finn[o]       = f2bf(v0 * s * lnf[t]);
    finn[o + 256] = f2bf(v1 * s * lnf[t + 256]);
    finn[o + 512] = f2bf(v2 * s * lnf[t + 512]);
}

// ---------------------------------------------------------------- pair scores v2 (fp32, deterministic)
__global__ __launch_bounds__(256) void pair_scores_k(const float* __restrict__ xnt,
                                                     float* __restrict__ partial) {
    __shared__ float As[16][64];
    __shared__ float Bs[4][16][64];
    __shared__ float rowmax[4][64];
    int ct = blockIdx.x;
    int p  = blockIdx.y;
    int b = p / 28, pp = p % 28;
    int i = 1; while (pp >= i) { pp -= i; i++; }
    int j = pp;
    const float* Abase = xnt + ((size_t)(b * cT) + i * cC + ct * 64) * cE;
    const float* Bbase = xnt + ((size_t)(b * cT) + j * cC) * cE;
    int tid = threadIdx.x, lane = tid & 63, w = tid >> 6;
    int ly = lane >> 3, lx = lane & 7;
    int srow = tid >> 2, skc = (tid & 3) << 2;
    const float* bw = Bbase + (size_t)(w * 64) * cE;

    float acc[8][8];
    #pragma unroll
    for (int a2 = 0; a2 < 8; a2++)
        #pragma unroll
        for (int b2 = 0; b2 < 8; b2++) acc[a2][b2] = 0.f;

    for (int k0 = 0; k0 < cE; k0 += 16) {
        float4 va = *(const float4*)(Abase + (size_t)srow * cE + k0 + skc);
        As[skc + 0][srow] = va.x; As[skc + 1][srow] = va.y;
        As[skc + 2][srow] = va.z; As[skc + 3][srow] = va.w;
        #pragma unroll
        for (int q = 0; q < 4; q++) {
            int id = (q << 6) + lane;
            int br = id >> 2, bkc = (id & 3) << 2;
            float4 vb = *(const float4*)(bw + (size_t)br * cE + k0 + bkc);
            Bs[w][bkc + 0][br] = vb.x; Bs[w][bkc + 1][br] = vb.y;
            Bs[w][bkc + 2][br] = vb.z; Bs[w][bkc + 3][br] = vb.w;
        }
        __syncthreads();
        #pragma unroll
        for (int k = 0; k < 16; k++) {
            float av[8], bv[8];
            *(float4*)&av[0] = *(float4*)&As[k][ly << 3];
            *(float4*)&av[4] = *(float4*)&As[k][(ly << 3) + 4];
            *(float4*)&bv[0] = *(float4*)&Bs[w][k][lx << 3];
            *(float4*)&bv[4] = *(float4*)&Bs[w][k][(lx << 3) + 4];
            #pragma unroll
            for (int r = 0; r < 8; r++)
                #pragma unroll
                for (int q = 0; q < 8; q++)
                    acc[r][q] = fmaf(av[r], bv[q], acc[r][q]);
        }
        __syncthreads();
    }
    #pragma unroll
    for (int r = 0; r < 8; r++) {
        float m = acc[r][0];
        #pragma unroll
        for (int q = 1; q < 8; q++) m = fmaxf(m, acc[r][q]);
        m = fmaxf(m, __shfl_xor(m, 1, 64));
        m = fmaxf(m, __shfl_xor(m, 2, 64));
        m = fmaxf(m, __shfl_xor(m, 4, 64));
        if (lx == 0) rowmax[w][(ly << 3) + r] = m;
    }
    __syncthreads();
    if (tid == 0) {
        float s = 0.f;
        for (int r = 0; r < 64; r++)
            s += fmaxf(fmaxf(rowmax[0][r], rowmax[1][r]),
                       fmaxf(rowmax[2][r], rowmax[3][r]));
        partial[p * 4 + ct] = s;
    }
}

// ---------------------------------------------------------------- top-k + sort + weights (unchanged)
__global__ void score_topk_k(const float* __restrict__ partial,
                             int* __restrict__ sidx, float* __restrict__ sw) {
    __shared__ float sc[2][8][8];
    int t = threadIdx.x;
    if (t < 56) {
        int b = t / 28, pp = t % 28;
        int i = 1; while (pp >= i) { pp -= i; i++; }
        int j = pp;
        sc[b][i][j] = partial[t * 4 + 0] + partial[t * 4 + 1] + partial[t * 4 + 2] + partial[t * 4 + 3];
    }
    __syncthreads();
    if (t < 16) {
        int b = t >> 3, i = t & 7;
        int nsel = i < 3 ? i : 3;
        if (nsel > 0) {
            float loc[7];
            for (int j2 = 0; j2 < i; j2++) loc[j2] = sc[b][i][j2];
            int idxs[3]; float vals[3];
            for (int s = 0; s < nsel; s++) {
                int am = 0; float mv = loc[0];
                for (int j2 = 1; j2 < i; j2++) if (loc[j2] > mv) { mv = loc[j2]; am = j2; }
                idxs[s] = am; vals[s] = mv; loc[am] = -1e30f;
            }
            for (int a = 0; a < nsel; a++)
                for (int c2 = a + 1; c2 < nsel; c2++)
                    if (idxs[c2] < idxs[a]) {
                        int ti = idxs[a]; idxs[a] = idxs[c2]; idxs[c2] = ti;
                        float tv = vals[a]; vals[a] = vals[c2]; vals[c2] = tv;
                    }
            float den = vals[0] + 1e-8f;
            for (int s = 0; s < nsel; s++) {
                sidx[(b * 8 + i) * 3 + s] = idxs[s];
                sw[(b * 8 + i) * 3 + s]   = vals[s] / den;
            }
        }
    }
}

// ---------------------------------------------------------------- assemble extended context h (fp32)
__global__ __launch_bounds__(192) void build_k(const float* __restrict__ x,
                                               const int* __restrict__ sidx,
                                               const float* __restrict__ sw,
                                               float* __restrict__ h) {
    int m = blockIdx.x, r = blockIdx.y;
    int b = m >> 3, i = m & 7;
    int nsel = i < 3 ? i : 3;
    int pad = cTL - (nsel + 1) * cC;
    int pos = r - pad;
    float4 val = make_float4(0.f, 0.f, 0.f, 0.f);
    if (pos >= 0) {
        if (pos < nsel * cC) {
            int s = pos >> 8;
            int jj = sidx[(b * 8 + i) * 3 + s];
            float wg = sw[(b * 8 + i) * 3 + s];
            const float4* src = (const float4*)(x + ((size_t)(b * cT) + jj * cC + (pos & 255)) * cE);
            float4 v = src[threadIdx.x];
            val = make_float4(v.x * wg, v.y * wg, v.z * wg, v.w * wg);
        } else {
            int c = pos - nsel * cC;
            const float4* src = (const float4*)(x + ((size_t)(b * cT) + i * cC + c) * cE);
            val = src[threadIdx.x];
        }
    }
    ((float4*)(h + ((size_t)m * cTL + r) * cE))[threadIdx.x] = val;
}

enum { GE_F32 = 0, GE_RELU = 1, GE_CS = 2, GE_ADDH = 3, GE_ANBT = 4 };

// ---------------------------------------------------------------- 256x256 MFMA GEMM v4: 8-phase schedule
// NT: C[m,n] = sum_k A[m*lda+k]*B[n*ldb+k]. BK=64, 2-buffer LDS (2x64KB), 8 waves (2Mx4N).
// swz: 3 = XCD owns m-chunk, sweeps n (small-B GEMMs); 4 = XCD owns n-chunk, sweeps m (logits: A small)
template <int EPI>
__global__ __launch_bounds__(512, 2) void gemm256(
        const u16* __restrict__ A, int lda,
        const u16* __restrict__ B, int ldb,
        void* __restrict__ Cv, int ldc, int K,
        const float* __restrict__ bias,
        u16* __restrict__ p0, u16* __restrict__ p1, u16* __restrict__ p2,
        int swz)
{
    __shared__ __align__(16) u16 lds[65536];   // 2 buffers x {A:16384, B:16384} u16
    int bx = blockIdx.x, by = blockIdx.y;
    if (swz == 3) {   // XCD owns gy/8 m-tiles; all XCDs sweep n in sync
        int gx = gridDim.x, gy = gridDim.y;
        int orig = by * gx + bx;
        int mpx = gy >> 3;
        int xcd = orig & 7, idx = orig >> 3;
        by = xcd * mpx + idx % mpx;
        bx = idx / mpx;
        (void)gx;
    } else if (swz == 4) {   // XCD owns contiguous n-chunk, sweeps m fastest (nwg%8==0)
        int gx = gridDim.x, gy = gridDim.y;
        int nwg = gx * gy;
        int orig = by * gx + bx;
        int wg = (orig & 7) * (nwg >> 3) + (orig >> 3);
        by = wg % gy;
        bx = wg / gy;
    }
    const int n0 = bx << 8, m0 = by << 8;
    const int tid = threadIdx.x, lane = tid & 63, w = tid >> 6;
    const int wm = w >> 2, wn = w & 3;

    const u16* Ab = A + (size_t)m0 * lda;
    const u16* Bb = B + (size_t)n0 * ldb;

    // staging: half-tile = 128 rows x 64 u16 (16KB); thread covers rows tid>>3 and +64, chunk tid&7
    const int srow0 = tid >> 3;                        // 0..63
    const int sq    = (tid & 7) ^ (srow0 & 7);         // pre-swizzled global 16B-chunk
    const int NT = K >> 6;

    auto STAGE = [&](int kt, int op, int half) {       // op: 0=A, 1=B
        const u16* base = op ? Bb : Ab;
        const int  ld   = op ? ldb : lda;
        const u16* src = base + (size_t)(half * 128 + srow0) * ld + (size_t)kt * 64 + sq * 8;
        u16* d = lds + ((kt & 1) << 15) + (op << 14) + (half << 13) + tid * 8;
        GLOAD16(src, d);
        GLOAD16(src + (size_t)64 * ld, d + 4096);
    };

    f32x4 acc[8][4];
    #pragma unroll
    for (int m = 0; m < 8; m++)
        #pragma unroll
        for (int n = 0; n < 4; n++) acc[m][n] = (f32x4){0.f, 0.f, 0.f, 0.f};

    const int l15 = lane & 15;
    const int klo = lane >> 4;                          // 0..3
    const int arow = (l15) * 64;                        // + mf*1024
    const int brow = ((wn & 1) * 64 + l15) * 64;        // + nf*1024
    const int abase = (wm << 13);
    const int bbase = 16384 + ((wn >> 1) << 13);

    // prologue: tile0 all 4 halves + tile1 B halves; wait tile0 (4 stay in flight)
    STAGE(0, 0, 0); STAGE(0, 0, 1); STAGE(0, 1, 0); STAGE(0, 1, 1);
    if (NT > 1) { STAGE(1, 1, 0); STAGE(1, 1, 1); }
    asm volatile("s_waitcnt vmcnt(4)" ::: "memory");
    BARRIER();

    for (int kt = 0; kt < NT; ++kt) {
        const int buf = (kt & 1) << 15;
        bf16x8 a0[4], a1[4], bf0[4], bf1[4];
        // ---- phase 0: B kk0 (4) + A m0-3 kk0 (4); stage (kt+1, A0)
        #pragma unroll
        for (int nf = 0; nf < 4; nf++)
            bf0[nf] = *(const bf16x8*)(lds + buf + bbase + brow + nf * 1024 + (((klo) ^ (l15 & 7)) << 3));
        #pragma unroll
        for (int mf = 0; mf < 4; mf++)
            a0[mf] = *(const bf16x8*)(lds + buf + abase + arow + mf * 1024 + (((klo) ^ (l15 & 7)) << 3));
        if (kt + 1 < NT) STAGE(kt + 1, 0, 0);
        BARRIER();
        __builtin_amdgcn_s_setprio(1);
        #pragma unroll
        for (int mf = 0; mf < 4; mf++)
            #pragma unroll
            for (int nf = 0; nf < 4; nf++)
                acc[mf][nf] = __builtin_amdgcn_mfma_f32_16x16x32_bf16(a0[mf], bf0[nf], acc[mf][nf], 0, 0, 0);
        __builtin_amdgcn_s_setprio(0);
        BARRIER();
        // ---- phase 1: A m4-7 kk0 (4); stage (kt+1, A1)
        #pragma unroll
        for (int mf = 0; mf < 4; mf++)
            a1[mf] = *(const bf16x8*)(lds + buf + abase + arow + (mf + 4) * 1024 + (((klo) ^ (l15 & 7)) << 3));
        if (kt + 1 < NT) STAGE(kt + 1, 0, 1);
        BARRIER();
        __builtin_amdgcn_s_setprio(1);
        #pragma unroll
        for (int mf = 0; mf < 4; mf++)
            #pragma unroll
            for (int nf = 0; nf < 4; nf++)
                acc[mf + 4][nf] = __builtin_amdgcn_mfma_f32_16x16x32_bf16(a1[mf], bf0[nf], acc[mf + 4][nf], 0, 0, 0);
        __builtin_amdgcn_s_setprio(0);
        BARRIER();
        // ---- phase 2: B kk1 (4) + A m0-3 kk1 (4); no stage
        #pragma unroll
        for (int nf = 0; nf < 4; nf++)
            bf1[nf] = *(const bf16x8*)(lds + buf + bbase + brow + nf * 1024 + (((4 + klo) ^ (l15 & 7)) << 3));
        #pragma unroll
        for (int mf = 0; mf < 4; mf++)
            a0[mf] = *(const bf16x8*)(lds + buf + abase + arow + mf * 1024 + (((4 + klo) ^ (l15 & 7)) << 3));
        BARRIER();
        __builtin_amdgcn_s_setprio(1);
        #pragma unroll
        for (int mf = 0; mf < 4; mf++)
            #pragma unroll
            for (int nf = 0; nf < 4; nf++)
                acc[mf][nf] = __builtin_amdgcn_mfma_f32_16x16x32_bf16(a0[mf], bf1[nf], acc[mf][nf], 0, 0, 0);
        __builtin_amdgcn_s_setprio(0);
        BARRIER();
        // ---- phase 3: A m4-7 kk1 (4); stage (kt+2, B0)+(kt+2, B1); vmcnt(4)
        #pragma unroll
        for (int mf = 0; mf < 4; mf++)
            a1[mf] = *(const bf16x8*)(lds + buf + abase + arow + (mf + 4) * 1024 + (((4 + klo) ^ (l15 & 7)) << 3));
        if (kt + 2 < NT) {
            STAGE(kt + 2, 1, 0); STAGE(kt + 2, 1, 1);
            asm volatile("s_waitcnt vmcnt(4)" ::: "memory");
        } else if (kt + 1 < NT) {
            asm volatile("s_waitcnt vmcnt(0)" ::: "memory");
        }
        BARRIER();
        __builtin_amdgcn_s_setprio(1);
        #pragma unroll
        for (int mf = 0; mf < 4; mf++)
            #pragma unroll
            for (int nf = 0; nf < 4; nf++)
                acc[mf + 4][nf] = __builtin_amdgcn_mfma_f32_16x16x32_bf16(a1[mf], bf1[nf], acc[mf + 4][nf], 0, 0, 0);
        __builtin_amdgcn_s_setprio(0);
        BARRIER();
    }

    // epilogue: C/D layout col=lane&15, row=(lane>>4)*4+j
    const int r0 = (lane >> 4) << 2;
    const int c0 = lane & 15;

    if constexpr (EPI == GE_F32) {
        float* Cb = (float*)Cv;
        #pragma unroll
        for (int mf = 0; mf < 8; mf++) {
            int gmb = m0 + (wm << 7) + (mf << 4) + r0;
            #pragma unroll
            for (int j = 0; j < 4; j++) {
                float* crow = Cb + (size_t)(gmb + j) * ldc;
                #pragma unroll
                for (int nf = 0; nf < 4; nf++)
                    crow[n0 + (wn << 6) + (nf << 4) + c0] = acc[mf][nf][j];
            }
        }
    } else if constexpr (EPI == GE_ADDH) {
        float* Cb = (float*)Cv;
        #pragma unroll
        for (int mf = 0; mf < 8; mf++) {
            int gmb = m0 + (wm << 7) + (mf << 4) + r0;
            #pragma unroll
            for (int j = 0; j < 4; j++) {
                float* crow = Cb + (size_t)(gmb + j) * ldc;
                #pragma unroll
                for (int nf = 0; nf < 4; nf++) {
                    int gn = n0 + (wn << 6) + (nf << 4) + c0;
                    crow[gn] = crow[gn] + acc[mf][nf][j] + bias[gn];
                }
            }
        }
    } else if constexpr (EPI == GE_RELU) {
        // coalesced via LDS: 4 chunks of 64 m-rows; write chunk to LDS, read out contiguous.
        const bool aregion = (n0 < cE);
        u16 (*L)[280] = (u16(*)[280])lds;   // 64 x 280 u16 = 35840 B; stride dodges 4-row bank collisions
        #pragma unroll
        for (int ch = 0; ch < 4; ch++) {
            BARRIER();                       // previous chunk fully read before overwrite
            if (wm == (ch >> 1)) {
                #pragma unroll
                for (int mi = 0; mi < 4; mi++) {
                    const int mf = ((ch & 1) << 2) + mi;
                    const int rloc = (mi << 4) + r0;
                    #pragma unroll
                    for (int nf = 0; nf < 4; nf++) {
                        const int coll = (wn << 6) + (nf << 4) + c0;
                        const float bv = bias[n0 + coll];
                        #pragma unroll
                        for (int j = 0; j < 4; j++) {
                            float tv = acc[mf][nf][j] + bv;
                            tv = fmaxf(tv, 0.f);
                            L[rloc + j][coll] = f2bf(tv * tv);
                        }
                    }
                }
            }
            BARRIER();
            const int gmch = m0 + (ch << 6);
            if (aregion) {
                // abuf: 64 rows x 256 cols, contiguous rows
                #pragma unroll
                for (int it = 0; it < 4; it++) {
                    int idx = (it << 9) + tid;               // 2048 slots = 64r x 32 col-groups
                    int r = idx >> 5, cg = (idx & 31) << 3;
                    *(uint4*)(p0 + (size_t)(gmch + r) * cE + n0 + cg) = *(uint4*)&L[r][cg];
                }
                // aTb: 256 gn-rows x 64 m-cols (transposed), contiguous along m
                const int zz = gmch >> 10, cmb = gmch & 1023;
                #pragma unroll
                for (int it = 0; it < 4; it++) {
                    int idx = (it << 9) + tid;               // 2048 slots = 256 gn x 8 m-groups
                    int gr = idx >> 3, mg = (idx & 7) << 3;
                    u16 tmp[8];
                    #pragma unroll
                    for (int q = 0; q < 8; q++) tmp[q] = L[mg + q][gr];
                    *(uint4*)(p1 + (size_t)zz * (cE * cTL) + (size_t)(n0 + gr) * cTL + cmb + mg) = *(uint4*)tmp;
                }
            } else {
                #pragma unroll
                for (int it = 0; it < 4; it++) {
                    int idx = (it << 9) + tid;
                    int r = idx >> 5, cg = (idx & 31) << 3;
                    *(uint4*)(p2 + (size_t)(gmch + r) * cPIN + (n0 - cE) + cg) = *(uint4*)&L[r][cg];
                }
            }
        }
    }
}

// ---------------------------------------------------------------- bf16 MFMA GEMM (128x128) for cs / a_newT(+fused tmul)
template <int EPI>
__global__ __launch_bounds__(256) void gemm_bt(
        const u16* __restrict__ A, int lda, size_t sA,
        const u16* __restrict__ B, int ldb, size_t sB,
        void* __restrict__ Cv, int ldc, size_t sC, int K,
        const float* __restrict__ invn,
        const float* __restrict__ sp,
        int kcap,
        u16* __restrict__ fiout)
{
    const int n0 = blockIdx.x << 7, m0 = blockIdx.y << 7, z = blockIdx.z;
    const int tid = threadIdx.x, lane = tid & 63, w = tid >> 6;
    const int wr = w >> 1, wc = w & 1;

    if constexpr (EPI == GE_CS) {
        if (n0 > m0) return;   // strictly-upper blocks never read downstream (K-capped consumer)
    }

    const int Keff = kcap ? ((K < n0 + 128) ? K : n0 + 128) : K;

    __shared__ __align__(16) u16 As[128 * 32];
    __shared__ __align__(16) u16 Bs[128 * 32];

    const u16* Ab = A + (size_t)z * sA + (size_t)m0 * lda;
    const u16* Bb = B + (size_t)z * sB + (size_t)n0 * ldb;

    const int srow = (w << 5) + (lane >> 2);
    const int skof = (lane & 3) << 3;
    const u16* ga0 = Ab + (size_t)srow * lda + skof;
    const u16* gb0 = Bb + (size_t)srow * ldb + skof;
    u16* la0 = As + (w << 10);
    u16* lb0 = Bs + (w << 10);

    f32x4 acc[4][4];
    #pragma unroll
    for (int m = 0; m < 4; m++)
        #pragma unroll
        for (int n = 0; n < 4; n++)
            acc[m][n] = (f32x4){0.f, 0.f, 0.f, 0.f};

    const int arow = (wr << 6) + (lane & 15);
    const int brow = (wc << 6) + (lane & 15);
    const int koff = (lane >> 4) << 3;

    for (int kt = 0; kt < Keff; kt += 32) {
        GLOAD16(ga0 + kt, la0);
        GLOAD16(ga0 + kt + (size_t)16 * lda, la0 + 512);
        GLOAD16(gb0 + kt, lb0);
        GLOAD16(gb0 + kt + (size_t)16 * ldb, lb0 + 512);
        __syncthreads();
        bf16x8 af[4], bfr[4];
        #pragma unroll
        for (int m = 0; m < 4; m++)
            af[m] = *(const bf16x8*)&As[(arow + (m << 4)) * 32 + koff];
        #pragma unroll
        for (int n = 0; n < 4; n++)
            bfr[n] = *(const bf16x8*)&Bs[(brow + (n << 4)) * 32 + koff];
        #pragma unroll
        for (int m = 0; m < 4; m++)
            #pragma unroll
            for (int n = 0; n < 4; n++)
                acc[m][n] = __builtin_amdgcn_mfma_f32_16x16x32_bf16(af[m], bfr[n], acc[m][n], 0, 0, 0);
        __syncthreads();
    }

    const int r0 = (lane >> 4) << 2;
    const int c0 = lane & 15;

    if constexpr (EPI == GE_ANBT) {
        // acc = a_newT tile: e = m0+..., m = n0+...  Fused: fi[z*TL+m][e] *= a_new[m][e]
        __shared__ u16 tr[128][129];
        #pragma unroll
        for (int m = 0; m < 4; m++) {
            int el = (wr << 6) + (m << 4) + r0;
            #pragma unroll
            for (int j = 0; j < 4; j++)
                #pragma unroll
                for (int n = 0; n < 4; n++)
                    tr[el + j][(wc << 6) + (n << 4) + c0] = f2bf(acc[m][n][j]);
        }
        __syncthreads();
        const int mrow = tid >> 1, e0h = (tid & 1) << 6;
        u16* fr = fiout + ((size_t)(z * cTL + n0 + mrow)) * cPIN + m0 + e0h;
        #pragma unroll
        for (int ee = 0; ee < 64; ee += 8) {
            uint4 fv = *(uint4*)(fr + ee);
            u16* pf = (u16*)&fv;
            u16 res[8];
            #pragma unroll
            for (int q = 0; q < 8; q++)
                res[q] = f2bf(bf2f(tr[e0h + ee + q][mrow]) * bf2f(pf[q]));
            *(uint4*)(fr + ee) = *(uint4*)res;
        }
    } else if constexpr (EPI == GE_CS) {
        u16* Cb = (u16*)Cv + (size_t)z * sC;
        const float* invz = invn + (z << 10);
        float inn[4];
        #pragma unroll
        for (int n = 0; n < 4; n++)
            inn[n] = invz[n0 + (wc << 6) + (n << 4) + c0];
        #pragma unroll
        for (int m = 0; m < 4; m++) {
            int gmb = m0 + (wr << 6) + (m << 4) + r0;
            #pragma unroll
            for (int j = 0; j < 4; j++) {
                int gm = gmb + j;
                float im = invz[gm];
                const float* spr = sp + (size_t)gm * cTL;
                u16* crow = Cb + (size_t)gm * ldc;
                #pragma unroll
                for (int n = 0; n < 4; n++) {
                    int gn = n0 + (wc << 6) + (n << 4) + c0;
                    float v = (gn <= gm) ? acc[m][n][j] * im * inn[n] * spr[gn] : 0.f;
                    crow[gn] = f2bf(v);
                }
            }
        }
    }
}

// ---------------------------------------------------------------- launch
extern "C" void kernel_launch(void* const* d_in, const int* in_sizes, int n_in,
                              void* d_out, int out_size, void* d_ws, size_t ws_size,
                              hipStream_t stream) {
    const int*   ids  = (const int*)d_in[0];
    const float* wte  = (const float*)d_in[1];
    const float* rmsw = (const float*)d_in[2];
    const float* enrw = (const float*)d_in[3];
    const float* enrb = (const float*)d_in[4];
    const float* sp   = (const float*)d_in[5];
    const float* fusw = (const float*)d_in[6];
    const float* fusb = (const float*)d_in[7];
    const float* lnfw = (const float*)d_in[8];
    float* out = (float*)d_out;

    // fp32 workspace
    float* ws   = (float*)d_ws;
    float* x    = ws;                      // 3,145,728
    float* xnt  = x    + 3145728;          // 3,145,728
    float* h    = xnt  + 3145728;          // 12,582,912
    float* invn = h    + 12582912;         // 16,384
    float* part = invn + 16384;            // 256
    float* swv  = part + 256;              // 64
    int*   sidx = (int*)(swv + 64);        // 64
    // bf16 workspace
    u16* wteb  = (u16*)(sidx + 64);        // 24,576,000
    u16* enrwb = wteb  + 24576000;         //  9,437,184
    u16* fuswb = enrwb + 9437184;          //  7,077,888
    u16* xnb   = fuswb + 7077888;          // 12,582,912 (reused as finn bf16)
    u16* abuf  = xnb   + 12582912;         // 12,582,912
    u16* aTb   = abuf  + 12582912;         // 12,582,912
    u16* fi    = aTb   + 12582912;         // 37,748,736
    u16* csb   = fi    + 37748736;         // 16,777,216
    u16* finnb = xnb;

    // 0. weight conversion fp32->bf16 (single launch)
    cvt3_k<<<(24576000 + 9437184 + 7077888) / 1024, 256, 0, stream>>>(
        wte, wteb, 24576000, enrw, enrwb, 9437184, fusw, fuswb, 7077888);

    // 1. embed + token normalize (fp32)
    embed_k<<<cB * cT, 256, 0, stream>>>(ids, wte, x, xnt);
    // 2. retrieval scores + top-k + assembly (fp32, deterministic)
    pair_scores_k<<<dim3(4, 56), 256, 0, stream>>>(xnt, part);
    score_topk_k<<<1, 64, 0, stream>>>(part, sidx, swv);
    build_k<<<dim3(cNCH, cTL), 192, 0, stream>>>(x, sidx, swv, h);

    // 3. layers
    for (int l = 0; l < cL; l++) {
        rmsnorm_bf_k<<<cMR, 256, 0, stream>>>(h, rmsw + (size_t)l * cE, xnb);
        // xp = relu(xn @ enr_w.T + b)^2 ; writes a (row-major + transposed) and b/x1 into fi
        gemm256<GE_RELU><<<dim3(cED / 256, cMR / 256), 512, 0, stream>>>(
            xnb, cE, enrwb + (size_t)l * cED * cE, cE,
            nullptr, 0, cE, enrb + (size_t)l * cED,
            abuf, aTb, fi, 3);
        invna_bf_k<<<cMR, 256, 0, stream>>>(abuf, invn);
        // M = tril(sp) * cosine(a,a)
        gemm_bt<GE_CS><<<dim3(8, 8, cNCH), 256, 0, stream>>>(
            abuf, cE, (size_t)cTL * cE, abuf, cE, (size_t)cTL * cE,
            csb, cTL, (size_t)cTL * cTL, cE,
            invn, sp + (size_t)l * cTL * cTL, 0, nullptr);
        // a_newT[e][m] = sum_c aT[e][c]*M[m][c] (K capped at n0+128); fused fi[m][e] *= result
        gemm_bt<GE_ANBT><<<dim3(8, 6, cNCH), 256, 0, stream>>>(
            aTb, cTL, (size_t)cE * cTL, csb, cTL, (size_t)cTL * cTL,
            nullptr, 0, 0, cTL,
            nullptr, nullptr, 1, fi);
        // h += fi @ fus_w.T + fus_b
        gemm256<GE_ADDH><<<dim3(cE / 256, cMR / 256), 512, 0, stream>>>(
            fi, cPIN, fuswb + (size_t)l * cE * cPIN, cPIN,
            h, cE, cPIN, fusb + (size_t)l * cE,
            nullptr, nullptr, nullptr, 3);
    }

    // 4. final norm + logits (A = finnb is only 6 MB -> n-chunked XCD map, m-fastest sweep)
    final_bf_k<<<cB * cT, 256, 0, stream>>>(h, lnfw, finnb);
    gemm256<GE_F32><<<dim3(cV / 256, (cB * cT) / 256), 512, 0, stream>>>(
        finnb, cE, wteb, cE, out, cV, cE,
        nullptr, nullptr, nullptr, nullptr, 4);
}

// Round 12
// 1686.739 us; speedup vs baseline: 1.0719x; 1.0719x over previous
//
#include <hip/hip_runtime.h>
#include <math.h>

typedef unsigned short u16;
typedef __attribute__((ext_vector_type(8))) short bf16x8;
typedef __attribute__((ext_vector_type(4))) float f32x4;

// Problem constants
constexpr int cV = 32000, cE = 768, cL = 4, cC = 256, cTL = 1024;
constexpr int cED = 3072, cPIN = 2304;
constexpr int cB = 2, cT = 2048, cN = 8, cNCH = 16, cMR = 16384;

// ---------------------------------------------------------------- bf16 helpers
__device__ inline float bf2f(u16 u) {
    union { uint32_t i; float f; } v; v.i = ((uint32_t)u) << 16; return v.f;
}
__device__ inline u16 f2bf(float f) {
    union { float f; uint32_t u; } v; v.f = f;
    uint32_t r = v.u + 0x7FFF + ((v.u >> 16) & 1);
    return (u16)(r >> 16);
}

// async global->LDS, 16B per lane; LDS dest is wave-uniform base + lane*16
#define GLOAD16(gp, lp) __builtin_amdgcn_global_load_lds( \
    (const __attribute__((address_space(1))) void*)(gp), \
    (__attribute__((address_space(3))) void*)(lp), 16, 0, 0)

#define BARRIER() asm volatile("s_barrier" ::: "memory")

// ---------------------------------------------------------------- reductions
__device__ inline float blockReduceSum256(float v, float* sbuf) {
    #pragma unroll
    for (int m = 1; m < 64; m <<= 1) v += __shfl_xor(v, m, 64);
    int lane = threadIdx.x & 63, w = threadIdx.x >> 6;
    if (lane == 0) sbuf[w] = v;
    __syncthreads();
    return sbuf[0] + sbuf[1] + sbuf[2] + sbuf[3];
}

// ---------------------------------------------------------------- fp32 -> bf16 bulk convert (3 arrays, 1 launch)
__global__ __launch_bounds__(256) void cvt3_k(const float* __restrict__ s0, u16* __restrict__ d0, long n0,
                                              const float* __restrict__ s1, u16* __restrict__ d1, long n1,
                                              const float* __restrict__ s2, u16* __restrict__ d2, long n2) {
    long i = ((long)blockIdx.x * 256 + threadIdx.x) * 4;
    const float* s; u16* d; long off;
    if (i < n0)           { s = s0; d = d0; off = i; }
    else if (i < n0 + n1) { s = s1; d = d1; off = i - n0; }
    else if (i < n0 + n1 + n2) { s = s2; d = d2; off = i - n0 - n1; }
    else return;
    float4 v = *(const float4*)(s + off);
    uint32_t lo = f2bf(v.x) | ((uint32_t)f2bf(v.y) << 16);
    uint32_t hi = f2bf(v.z) | ((uint32_t)f2bf(v.w) << 16);
    *(uint2*)(d + off) = make_uint2(lo, hi);
}

// ---------------------------------------------------------------- embed + token-normalize (fp32, feeds topk)
__global__ __launch_bounds__(256) void embed_k(const int* __restrict__ ids,
                                               const float* __restrict__ wte,
                                               float* __restrict__ x,
                                               float* __restrict__ xnt) {
    __shared__ float sb[4];
    int tok = blockIdx.x;
    const float* src = wte + (size_t)ids[tok] * cE;
    int t = threadIdx.x;
    float v0 = src[t], v1 = src[t + 256], v2 = src[t + 512];
    float tot = blockReduceSum256(v0 * v0 + v1 * v1 + v2 * v2, sb);
    float inv = 1.0f / (sqrtf(tot) + 1e-8f);
    size_t o = (size_t)tok * cE + t;
    x[o] = v0; x[o + 256] = v1; x[o + 512] = v2;
    xnt[o] = v0 * inv; xnt[o + 256] = v1 * inv; xnt[o + 512] = v2 * inv;
}

// ---------------------------------------------------------------- rmsnorm -> bf16
__global__ __launch_bounds__(256) void rmsnorm_bf_k(const float* __restrict__ in,
                                                    const float* __restrict__ w,
                                                    u16* __restrict__ out) {
    __shared__ float sb[4];
    size_t row = blockIdx.x;
    const float* src = in + row * cE;
    int t = threadIdx.x;
    float v0 = src[t], v1 = src[t + 256], v2 = src[t + 512];
    float tot = blockReduceSum256(v0 * v0 + v1 * v1 + v2 * v2, sb);
    float s = 1.0f / sqrtf(tot * (1.0f / cE) + 1e-10f);
    out[row * cE + t]       = f2bf(v0 * s * w[t]);
    out[row * cE + t + 256] = f2bf(v1 * s * w[t + 256]);
    out[row * cE + t + 512] = f2bf(v2 * s * w[t + 512]);
}

// ---------------------------------------------------------------- inverse row norm of a (bf16 input)
__global__ __launch_bounds__(256) void invna_bf_k(const u16* __restrict__ a,
                                                  float* __restrict__ invna) {
    __shared__ float sb[4];
    size_t row = blockIdx.x;
    const u16* src = a + row * cE;
    int t = threadIdx.x;
    float v0 = bf2f(src[t]), v1 = bf2f(src[t + 256]), v2 = bf2f(src[t + 512]);
    float tot = blockReduceSum256(v0 * v0 + v1 * v1 + v2 * v2, sb);
    if (t == 0) invna[row] = 1.0f / sqrtf(tot + 1e-8f);
}

// ---------------------------------------------------------------- final row extract + rmsnorm(lnf) -> bf16
__global__ __launch_bounds__(256) void final_bf_k(const float* __restrict__ h,
                                                  const float* __restrict__ lnf,
                                                  u16* __restrict__ finn) {
    __shared__ float sb[4];
    int tok = blockIdx.x;
    int b = tok >> 11, tt = tok & 2047;
    int i = tt >> 8, c = tt & 255;
    size_t row = (size_t)(b * cN + i) * cTL + (cTL - cC) + c;
    const float* src = h + row * cE;
    int t = threadIdx.x;
    float v0 = src[t], v1 = src[t + 256], v2 = src[t + 512];
    float tot = blockReduceSum256(v0 * v0 + v1 * v1 + v2 * v2, sb);
    float s = 1.0f / sqrtf(tot * (1.0f / cE) + 1e-10f);
    size_t o = (size_t)tok * cE + t;
    finn[o]       = f2bf(v0 * s * lnf[t]);
    finn[o + 256] = f2bf(v1 * s * lnf[t + 256]);
    finn[o + 512] = f2bf(v2 * s * lnf[t + 512]);
}

// ---------------------------------------------------------------- pair scores v2 (fp32, deterministic)
__global__ __launch_bounds__(256) void pair_scores_k(const float* __restrict__ xnt,
                                                     float* __restrict__ partial) {
    __shared__ float As[16][64];
    __shared__ float Bs[4][16][64];
    __shared__ float rowmax[4][64];
    int ct = blockIdx.x;
    int p  = blockIdx.y;
    int b = p / 28, pp = p % 28;
    int i = 1; while (pp >= i) { pp -= i; i++; }
    int j = pp;
    const float* Abase = xnt + ((size_t)(b * cT) + i * cC + ct * 64) * cE;
    const float* Bbase = xnt + ((size_t)(b * cT) + j * cC) * cE;
    int tid = threadIdx.x, lane = tid & 63, w = tid >> 6;
    int ly = lane >> 3, lx = lane & 7;
    int srow = tid >> 2, skc = (tid & 3) << 2;
    const float* bw = Bbase + (size_t)(w * 64) * cE;

    float acc[8][8];
    #pragma unroll
    for (int a2 = 0; a2 < 8; a2++)
        #pragma unroll
        for (int b2 = 0; b2 < 8; b2++) acc[a2][b2] = 0.f;

    for (int k0 = 0; k0 < cE; k0 += 16) {
        float4 va = *(const float4*)(Abase + (size_t)srow * cE + k0 + skc);
        As[skc + 0][srow] = va.x; As[skc + 1][srow] = va.y;
        As[skc + 2][srow] = va.z; As[skc + 3][srow] = va.w;
        #pragma unroll
        for (int q = 0; q < 4; q++) {
            int id = (q << 6) + lane;
            int br = id >> 2, bkc = (id & 3) << 2;
            float4 vb = *(const float4*)(bw + (size_t)br * cE + k0 + bkc);
            Bs[w][bkc + 0][br] = vb.x; Bs[w][bkc + 1][br] = vb.y;
            Bs[w][bkc + 2][br] = vb.z; Bs[w][bkc + 3][br] = vb.w;
        }
        __syncthreads();
        #pragma unroll
        for (int k = 0; k < 16; k++) {
            float av[8], bv[8];
            *(float4*)&av[0] = *(float4*)&As[k][ly << 3];
            *(float4*)&av[4] = *(float4*)&As[k][(ly << 3) + 4];
            *(float4*)&bv[0] = *(float4*)&Bs[w][k][lx << 3];
            *(float4*)&bv[4] = *(float4*)&Bs[w][k][(lx << 3) + 4];
            #pragma unroll
            for (int r = 0; r < 8; r++)
                #pragma unroll
                for (int q = 0; q < 8; q++)
                    acc[r][q] = fmaf(av[r], bv[q], acc[r][q]);
        }
        __syncthreads();
    }
    #pragma unroll
    for (int r = 0; r < 8; r++) {
        float m = acc[r][0];
        #pragma unroll
        for (int q = 1; q < 8; q++) m = fmaxf(m, acc[r][q]);
        m = fmaxf(m, __shfl_xor(m, 1, 64));
        m = fmaxf(m, __shfl_xor(m, 2, 64));
        m = fmaxf(m, __shfl_xor(m, 4, 64));
        if (lx == 0) rowmax[w][(ly << 3) + r] = m;
    }
    __syncthreads();
    if (tid == 0) {
        float s = 0.f;
        for (int r = 0; r < 64; r++)
            s += fmaxf(fmaxf(rowmax[0][r], rowmax[1][r]),
                       fmaxf(rowmax[2][r], rowmax[3][r]));
        partial[p * 4 + ct] = s;
    }
}

// ---------------------------------------------------------------- top-k + sort + weights (unchanged)
__global__ void score_topk_k(const float* __restrict__ partial,
                             int* __restrict__ sidx, float* __restrict__ sw) {
    __shared__ float sc[2][8][8];
    int t = threadIdx.x;
    if (t < 56) {
        int b = t / 28, pp = t % 28;
        int i = 1; while (pp >= i) { pp -= i; i++; }
        int j = pp;
        sc[b][i][j] = partial[t * 4 + 0] + partial[t * 4 + 1] + partial[t * 4 + 2] + partial[t * 4 + 3];
    }
    __syncthreads();
    if (t < 16) {
        int b = t >> 3, i = t & 7;
        int nsel = i < 3 ? i : 3;
        if (nsel > 0) {
            float loc[7];
            for (int j2 = 0; j2 < i; j2++) loc[j2] = sc[b][i][j2];
            int idxs[3]; float vals[3];
            for (int s = 0; s < nsel; s++) {
                int am = 0; float mv = loc[0];
                for (int j2 = 1; j2 < i; j2++) if (loc[j2] > mv) { mv = loc[j2]; am = j2; }
                idxs[s] = am; vals[s] = mv; loc[am] = -1e30f;
            }
            for (int a = 0; a < nsel; a++)
                for (int c2 = a + 1; c2 < nsel; c2++)
                    if (idxs[c2] < idxs[a]) {
                        int ti = idxs[a]; idxs[a] = idxs[c2]; idxs[c2] = ti;
                        float tv = vals[a]; vals[a] = vals[c2]; vals[c2] = tv;
                    }
            float den = vals[0] + 1e-8f;
            for (int s = 0; s < nsel; s++) {
                sidx[(b * 8 + i) * 3 + s] = idxs[s];
                sw[(b * 8 + i) * 3 + s]   = vals[s] / den;
            }
        }
    }
}

// ---------------------------------------------------------------- assemble extended context h (fp32)
__global__ __launch_bounds__(192) void build_k(const float* __restrict__ x,
                                               const int* __restrict__ sidx,
                                               const float* __restrict__ sw,
                                               float* __restrict__ h) {
    int m = blockIdx.x, r = blockIdx.y;
    int b = m >> 3, i = m & 7;
    int nsel = i < 3 ? i : 3;
    int pad = cTL - (nsel + 1) * cC;
    int pos = r - pad;
    float4 val = make_float4(0.f, 0.f, 0.f, 0.f);
    if (pos >= 0) {
        if (pos < nsel * cC) {
            int s = pos >> 8;
            int jj = sidx[(b * 8 + i) * 3 + s];
            float wg = sw[(b * 8 + i) * 3 + s];
            const float4* src = (const float4*)(x + ((size_t)(b * cT) + jj * cC + (pos & 255)) * cE);
            float4 v = src[threadIdx.x];
            val = make_float4(v.x * wg, v.y * wg, v.z * wg, v.w * wg);
        } else {
            int c = pos - nsel * cC;
            const float4* src = (const float4*)(x + ((size_t)(b * cT) + i * cC + c) * cE);
            val = src[threadIdx.x];
        }
    }
    ((float4*)(h + ((size_t)m * cTL + r) * cE))[threadIdx.x] = val;
}

enum { GE_F32 = 0, GE_RELU = 1, GE_CS = 2, GE_ADDH = 3, GE_ANBT = 4 };

// ---------------------------------------------------------------- 256x256 MFMA GEMM: 8-phase schedule, batched
// NT: C[m,n] = sum_k A[z*sA + m*lda + k] * B[z*sB + n*ldb + k]. BK=64, 2-buffer LDS, 8 waves (2Mx4N).
// kcap: Keff = min(K, n0+256) (tril consumer). GE_CS: skip n0>m0 tiles (never read downstream).
template <int EPI>
__global__ __launch_bounds__(512, 2) void gemm256(
        const u16* __restrict__ A, int lda, size_t sA,
        const u16* __restrict__ B, int ldb, size_t sB,
        void* __restrict__ Cv, int ldc, size_t sC, int K,
        const float* __restrict__ bias,
        u16* __restrict__ p0, u16* __restrict__ p1, u16* __restrict__ p2,
        const float* __restrict__ invn, const float* __restrict__ sp,
        int swz, int kcap)
{
    __shared__ __align__(16) u16 lds[65536];   // 2 buffers x {A:16384, B:16384} u16 (128 KB)
    int bx = blockIdx.x, by = blockIdx.y;
    const int z = blockIdx.z;
    if (swz == 3) {   // XCD owns gy/8 m-tiles; all XCDs sweep n in sync
        int gx = gridDim.x, gy = gridDim.y;
        int orig = by * gx + bx;
        int mpx = gy >> 3;
        int xcd = orig & 7, idx = orig >> 3;
        by = xcd * mpx + idx % mpx;
        bx = idx / mpx;
        (void)gx;
    }
    const int n0 = bx << 8, m0 = by << 8;
    const int tid = threadIdx.x, lane = tid & 63, w = tid >> 6;
    const int wm = w >> 2, wn = w & 3;

    if constexpr (EPI == GE_CS) {
        if (n0 > m0) return;   // strictly-upper 256-tile: never read (K-capped consumer)
    }

    const int Keff = kcap ? ((K < n0 + 256) ? K : n0 + 256) : K;
    const int NT = Keff >> 6;

    const u16* Ab = A + z * sA + (size_t)m0 * lda;
    const u16* Bb = B + z * sB + (size_t)n0 * ldb;

    // staging: half-tile = 128 rows x 64 u16 (16KB); thread covers rows tid>>3 and +64, chunk tid&7
    const int srow0 = tid >> 3;                        // 0..63
    const int sq    = (tid & 7) ^ (srow0 & 7);         // pre-swizzled global 16B-chunk

    auto STAGE = [&](int kt, int op, int half) {       // op: 0=A, 1=B
        const u16* base = op ? Bb : Ab;
        const int  ld   = op ? ldb : lda;
        const u16* src = base + (size_t)(half * 128 + srow0) * ld + (size_t)kt * 64 + sq * 8;
        u16* d = lds + ((kt & 1) << 15) + (op << 14) + (half << 13) + tid * 8;
        GLOAD16(src, d);
        GLOAD16(src + (size_t)64 * ld, d + 4096);
    };

    f32x4 acc[8][4];
    #pragma unroll
    for (int m = 0; m < 8; m++)
        #pragma unroll
        for (int n = 0; n < 4; n++) acc[m][n] = (f32x4){0.f, 0.f, 0.f, 0.f};

    const int l15 = lane & 15;
    const int klo = lane >> 4;                          // 0..3
    const int arow = (l15) * 64;                        // + mf*1024
    const int brow = ((wn & 1) * 64 + l15) * 64;        // + nf*1024
    const int abase = (wm << 13);
    const int bbase = 16384 + ((wn >> 1) << 13);

    // prologue: tile0 all 4 halves + tile1 B halves; wait tile0 (4 stay in flight)
    STAGE(0, 0, 0); STAGE(0, 0, 1); STAGE(0, 1, 0); STAGE(0, 1, 1);
    if (NT > 1) { STAGE(1, 1, 0); STAGE(1, 1, 1); }
    asm volatile("s_waitcnt vmcnt(4)" ::: "memory");
    BARRIER();

    for (int kt = 0; kt < NT; ++kt) {
        const int buf = (kt & 1) << 15;
        bf16x8 a0[4], a1[4], bf0[4], bf1[4];
        // ---- phase 0: B kk0 (4) + A m0-3 kk0 (4); stage (kt+1, A0)
        #pragma unroll
        for (int nf = 0; nf < 4; nf++)
            bf0[nf] = *(const bf16x8*)(lds + buf + bbase + brow + nf * 1024 + (((klo) ^ (l15 & 7)) << 3));
        #pragma unroll
        for (int mf = 0; mf < 4; mf++)
            a0[mf] = *(const bf16x8*)(lds + buf + abase + arow + mf * 1024 + (((klo) ^ (l15 & 7)) << 3));
        if (kt + 1 < NT) STAGE(kt + 1, 0, 0);
        BARRIER();
        __builtin_amdgcn_s_setprio(1);
        #pragma unroll
        for (int mf = 0; mf < 4; mf++)
            #pragma unroll
            for (int nf = 0; nf < 4; nf++)
                acc[mf][nf] = __builtin_amdgcn_mfma_f32_16x16x32_bf16(a0[mf], bf0[nf], acc[mf][nf], 0, 0, 0);
        __builtin_amdgcn_s_setprio(0);
        BARRIER();
        // ---- phase 1: A m4-7 kk0 (4); stage (kt+1, A1)
        #pragma unroll
        for (int mf = 0; mf < 4; mf++)
            a1[mf] = *(const bf16x8*)(lds + buf + abase + arow + (mf + 4) * 1024 + (((klo) ^ (l15 & 7)) << 3));
        if (kt + 1 < NT) STAGE(kt + 1, 0, 1);
        BARRIER();
        __builtin_amdgcn_s_setprio(1);
        #pragma unroll
        for (int mf = 0; mf < 4; mf++)
            #pragma unroll
            for (int nf = 0; nf < 4; nf++)
                acc[mf + 4][nf] = __builtin_amdgcn_mfma_f32_16x16x32_bf16(a1[mf], bf0[nf], acc[mf + 4][nf], 0, 0, 0);
        __builtin_amdgcn_s_setprio(0);
        BARRIER();
        // ---- phase 2: B kk1 (4) + A m0-3 kk1 (4); no stage
        #pragma unroll
        for (int nf = 0; nf < 4; nf++)
            bf1[nf] = *(const bf16x8*)(lds + buf + bbase + brow + nf * 1024 + (((4 + klo) ^ (l15 & 7)) << 3));
        #pragma unroll
        for (int mf = 0; mf < 4; mf++)
            a0[mf] = *(const bf16x8*)(lds + buf + abase + arow + mf * 1024 + (((4 + klo) ^ (l15 & 7)) << 3));
        BARRIER();
        __builtin_amdgcn_s_setprio(1);
        #pragma unroll
        for (int mf = 0; mf < 4; mf++)
            #pragma unroll
            for (int nf = 0; nf < 4; nf++)
                acc[mf][nf] = __builtin_amdgcn_mfma_f32_16x16x32_bf16(a0[mf], bf1[nf], acc[mf][nf], 0, 0, 0);
        __builtin_amdgcn_s_setprio(0);
        BARRIER();
        // ---- phase 3: A m4-7 kk1 (4); stage (kt+2, B0)+(kt+2, B1); vmcnt(4)
        #pragma unroll
        for (int mf = 0; mf < 4; mf++)
            a1[mf] = *(const bf16x8*)(lds + buf + abase + arow + (mf + 4) * 1024 + (((4 + klo) ^ (l15 & 7)) << 3));
        if (kt + 2 < NT) {
            STAGE(kt + 2, 1, 0); STAGE(kt + 2, 1, 1);
            asm volatile("s_waitcnt vmcnt(4)" ::: "memory");
        } else if (kt + 1 < NT) {
            asm volatile("s_waitcnt vmcnt(0)" ::: "memory");
        }
        BARRIER();
        __builtin_amdgcn_s_setprio(1);
        #pragma unroll
        for (int mf = 0; mf < 4; mf++)
            #pragma unroll
            for (int nf = 0; nf < 4; nf++)
                acc[mf + 4][nf] = __builtin_amdgcn_mfma_f32_16x16x32_bf16(a1[mf], bf1[nf], acc[mf + 4][nf], 0, 0, 0);
        __builtin_amdgcn_s_setprio(0);
        BARRIER();
    }

    // epilogue: C/D layout col=lane&15, row=(lane>>4)*4+j
    const int r0 = (lane >> 4) << 2;
    const int c0 = lane & 15;

    if constexpr (EPI == GE_F32) {
        float* Cb = (float*)Cv;
        #pragma unroll
        for (int mf = 0; mf < 8; mf++) {
            int gmb = m0 + (wm << 7) + (mf << 4) + r0;
            #pragma unroll
            for (int j = 0; j < 4; j++) {
                float* crow = Cb + (size_t)(gmb + j) * ldc;
                #pragma unroll
                for (int nf = 0; nf < 4; nf++)
                    crow[n0 + (wn << 6) + (nf << 4) + c0] = acc[mf][nf][j];
            }
        }
    } else if constexpr (EPI == GE_ADDH) {
        float* Cb = (float*)Cv;
        #pragma unroll
        for (int mf = 0; mf < 8; mf++) {
            int gmb = m0 + (wm << 7) + (mf << 4) + r0;
            #pragma unroll
            for (int j = 0; j < 4; j++) {
                float* crow = Cb + (size_t)(gmb + j) * ldc;
                #pragma unroll
                for (int nf = 0; nf < 4; nf++) {
                    int gn = n0 + (wn << 6) + (nf << 4) + c0;
                    crow[gn] = crow[gn] + acc[mf][nf][j] + bias[gn];
                }
            }
        }
    } else if constexpr (EPI == GE_RELU) {
        const bool aregion = (n0 < cE);
        #pragma unroll
        for (int mf = 0; mf < 8; mf++) {
            const int gmb = m0 + (wm << 7) + (mf << 4) + r0;
            const int zz = gmb >> 10, cm = gmb & 1023;
            #pragma unroll
            for (int nf = 0; nf < 4; nf++) {
                const int gn = n0 + (wn << 6) + (nf << 4) + c0;
                const float bv = bias[gn];
                u16 rb[4];
                #pragma unroll
                for (int j = 0; j < 4; j++) {
                    float tv = acc[mf][nf][j] + bv;
                    tv = fmaxf(tv, 0.f);
                    rb[j] = f2bf(tv * tv);
                }
                if (aregion) {
                    #pragma unroll
                    for (int j = 0; j < 4; j++)
                        p0[(size_t)(gmb + j) * cE + gn] = rb[j];
                    uint32_t lo = rb[0] | ((uint32_t)rb[1] << 16);
                    uint32_t hi = rb[2] | ((uint32_t)rb[3] << 16);
                    *(uint2*)&p1[(size_t)zz * (cE * cTL) + (size_t)gn * cTL + cm] = make_uint2(lo, hi);
                } else {
                    #pragma unroll
                    for (int j = 0; j < 4; j++)
                        p2[(size_t)(gmb + j) * cPIN + (gn - cE)] = rb[j];
                }
            }
        }
    } else if constexpr (EPI == GE_CS) {
        u16* Cb = (u16*)Cv + z * sC;
        const float* invz = invn + (z << 10);
        float inn[4];
        #pragma unroll
        for (int nf = 0; nf < 4; nf++)
            inn[nf] = invz[n0 + (wn << 6) + (nf << 4) + c0];
        #pragma unroll
        for (int mf = 0; mf < 8; mf++) {
            int gmb = m0 + (wm << 7) + (mf << 4) + r0;
            #pragma unroll
            for (int j = 0; j < 4; j++) {
                int gm = gmb + j;
                float im = invz[gm];
                const float* spr = sp + (size_t)gm * cTL;
                u16* crow = Cb + (size_t)gm * ldc;
                #pragma unroll
                for (int nf = 0; nf < 4; nf++) {
                    int gn = n0 + (wn << 6) + (nf << 4) + c0;
                    float v = (gn <= gm) ? acc[mf][nf][j] * im * inn[nf] * spr[gn] : 0.f;
                    crow[gn] = f2bf(v);
                }
            }
        }
    } else if constexpr (EPI == GE_ANBT) {
        // acc = a_newT tile: e = m0 + wm*128 + mf*16 + r0 + j, m = n0 + wn*64 + nf*16 + c0
        // Fused: fi[z*TL + m][e] *= a_new; transpose through LDS in 2 e-chunks of 128.
        u16 (*tr)[136] = (u16(*)[136])lds;   // 256(m) x 136(e) u16 = 69.6 KB of 128 KB
        #pragma unroll
        for (int ch = 0; ch < 2; ch++) {
            BARRIER();                        // pipeline LDS / previous chunk fully read
            if (wm == ch) {
                #pragma unroll
                for (int mf = 0; mf < 8; mf++) {
                    const int el = (mf << 4) + r0;              // 0..127 within chunk
                    #pragma unroll
                    for (int nf = 0; nf < 4; nf++) {
                        const int ml = (wn << 6) + (nf << 4) + c0;   // 0..255
                        u16 t0 = f2bf(acc[mf][nf][0]), t1 = f2bf(acc[mf][nf][1]);
                        u16 t2 = f2bf(acc[mf][nf][2]), t3 = f2bf(acc[mf][nf][3]);
                        *(uint2*)&tr[ml][el] = make_uint2(t0 | ((uint32_t)t1 << 16),
                                                          t2 | ((uint32_t)t3 << 16));
                    }
                }
            }
            BARRIER();
            const int ebase = m0 + (ch << 7);
            #pragma unroll
            for (int it = 0; it < 8; it++) {
                int idx = (it << 9) + tid;        // 4096 slots = 256 m x 16 e-groups
                int mrow = idx >> 4, eg = (idx & 15) << 3;
                u16* fr = p0 + ((size_t)(z * cTL + n0 + mrow)) * cPIN + ebase + eg;
                uint4 fv = *(uint4*)fr;
                u16* pf = (u16*)&fv;
                u16 res[8];
                #pragma unroll
                for (int q = 0; q < 8; q++)
                    res[q] = f2bf(bf2f(tr[mrow][eg + q]) * bf2f(pf[q]));
                *(uint4*)fr = *(uint4*)res;
            }
        }
    }
}

// ---------------------------------------------------------------- launch
extern "C" void kernel_launch(void* const* d_in, const int* in_sizes, int n_in,
                              void* d_out, int out_size, void* d_ws, size_t ws_size,
                              hipStream_t stream) {
    const int*   ids  = (const int*)d_in[0];
    const float* wte  = (const float*)d_in[1];
    const float* rmsw = (const float*)d_in[2];
    const float* enrw = (const float*)d_in[3];
    const float* enrb = (const float*)d_in[4];
    const float* sp   = (const float*)d_in[5];
    const float* fusw = (const float*)d_in[6];
    const float* fusb = (const float*)d_in[7];
    const float* lnfw = (const float*)d_in[8];
    float* out = (float*)d_out;

    // fp32 workspace
    float* ws   = (float*)d_ws;
    float* x    = ws;                      // 3,145,728
    float* xnt  = x    + 3145728;          // 3,145,728
    float* h    = xnt  + 3145728;          // 12,582,912
    float* invn = h    + 12582912;         // 16,384
    float* part = invn + 16384;            // 256
    float* swv  = part + 256;              // 64
    int*   sidx = (int*)(swv + 64);        // 64
    // bf16 workspace
    u16* wteb  = (u16*)(sidx + 64);        // 24,576,000
    u16* enrwb = wteb  + 24576000;         //  9,437,184
    u16* fuswb = enrwb + 9437184;          //  7,077,888
    u16* xnb   = fuswb + 7077888;          // 12,582,912 (reused as finn bf16)
    u16* abuf  = xnb   + 12582912;         // 12,582,912
    u16* aTb   = abuf  + 12582912;         // 12,582,912
    u16* fi    = aTb   + 12582912;         // 37,748,736
    u16* csb   = fi    + 37748736;         // 16,777,216
    u16* finnb = xnb;

    // 0. weight conversion fp32->bf16 (single launch)
    cvt3_k<<<(24576000 + 9437184 + 7077888) / 1024, 256, 0, stream>>>(
        wte, wteb, 24576000, enrw, enrwb, 9437184, fusw, fuswb, 7077888);

    // 1. embed + token normalize (fp32)
    embed_k<<<cB * cT, 256, 0, stream>>>(ids, wte, x, xnt);
    // 2. retrieval scores + top-k + assembly (fp32, deterministic)
    pair_scores_k<<<dim3(4, 56), 256, 0, stream>>>(xnt, part);
    score_topk_k<<<1, 64, 0, stream>>>(part, sidx, swv);
    build_k<<<dim3(cNCH, cTL), 192, 0, stream>>>(x, sidx, swv, h);

    // 3. layers
    for (int l = 0; l < cL; l++) {
        rmsnorm_bf_k<<<cMR, 256, 0, stream>>>(h, rmsw + (size_t)l * cE, xnb);
        // xp = relu(xn @ enr_w.T + b)^2 ; writes a (row-major + transposed) and b/x1 into fi
        gemm256<GE_RELU><<<dim3(cED / 256, cMR / 256, 1), 512, 0, stream>>>(
            xnb, cE, 0, enrwb + (size_t)l * cED * cE, cE, 0,
            nullptr, 0, 0, cE, enrb + (size_t)l * cED,
            abuf, aTb, fi, nullptr, nullptr, 3, 0);
        invna_bf_k<<<cMR, 256, 0, stream>>>(abuf, invn);
        // M = tril(sp) * cosine(a,a)   (batched 256-tile; upper tiles skipped)
        gemm256<GE_CS><<<dim3(4, 4, cNCH), 512, 0, stream>>>(
            abuf, cE, (size_t)cTL * cE, abuf, cE, (size_t)cTL * cE,
            csb, cTL, (size_t)cTL * cTL, cE, nullptr,
            nullptr, nullptr, nullptr, invn, sp + (size_t)l * cTL * cTL, 0, 0);
        // a_newT[e][m] = sum_c aT[e][c]*M[m][c] (K capped at n0+256); fused fi[m][e] *= result
        gemm256<GE_ANBT><<<dim3(4, 3, cNCH), 512, 0, stream>>>(
            aTb, cTL, (size_t)cE * cTL, csb, cTL, (size_t)cTL * cTL,
            nullptr, 0, 0, cTL, nullptr,
            fi, nullptr, nullptr, nullptr, nullptr, 0, 1);
        // h += fi @ fus_w.T + fus_b
        gemm256<GE_ADDH><<<dim3(cE / 256, cMR / 256, 1), 512, 0, stream>>>(
            fi, cPIN, 0, fuswb + (size_t)l * cE * cPIN, cPIN, 0,
            h, cE, 0, cPIN, fusb + (size_t)l * cE,
            nullptr, nullptr, nullptr, nullptr, nullptr, 3, 0);
    }

    // 4. final norm + logits
    final_bf_k<<<cB * cT, 256, 0, stream>>>(h, lnfw, finnb);
    gemm256<GE_F32><<<dim3(cV / 256, (cB * cT) / 256, 1), 512, 0, stream>>>(
        finnb, cE, 0, wteb, cE, 0, out, cV, 0, cE,
        nullptr, nullptr, nullptr, nullptr, nullptr, nullptr, 3, 0);
}

// Round 13
// 1663.118 us; speedup vs baseline: 1.0872x; 1.0142x over previous
//
#include <hip/hip_runtime.h>
#include <math.h>

typedef unsigned short u16;
typedef __attribute__((ext_vector_type(8))) short bf16x8;
typedef __attribute__((ext_vector_type(4))) float f32x4;

// Problem constants
constexpr int cV = 32000, cE = 768, cL = 4, cC = 256, cTL = 1024;
constexpr int cED = 3072, cPIN = 2304;
constexpr int cB = 2, cT = 2048, cN = 8, cNCH = 16, cMR = 16384;

// ---------------------------------------------------------------- bf16 helpers
__device__ inline float bf2f(u16 u) {
    union { uint32_t i; float f; } v; v.i = ((uint32_t)u) << 16; return v.f;
}
__device__ inline u16 f2bf(float f) {
    union { float f; uint32_t u; } v; v.f = f;
    uint32_t r = v.u + 0x7FFF + ((v.u >> 16) & 1);
    return (u16)(r >> 16);
}

// async global->LDS, 16B per lane; LDS dest is wave-uniform base + lane*16
#define GLOAD16(gp, lp) __builtin_amdgcn_global_load_lds( \
    (const __attribute__((address_space(1))) void*)(gp), \
    (__attribute__((address_space(3))) void*)(lp), 16, 0, 0)

#define BARRIER() asm volatile("s_barrier" ::: "memory")

// ---------------------------------------------------------------- reductions
__device__ inline float blockReduceSum256(float v, float* sbuf) {
    #pragma unroll
    for (int m = 1; m < 64; m <<= 1) v += __shfl_xor(v, m, 64);
    int lane = threadIdx.x & 63, w = threadIdx.x >> 6;
    if (lane == 0) sbuf[w] = v;
    __syncthreads();
    return sbuf[0] + sbuf[1] + sbuf[2] + sbuf[3];
}

// ---------------------------------------------------------------- fp32 -> bf16 bulk convert (3 arrays, 1 launch)
__global__ __launch_bounds__(256) void cvt3_k(const float* __restrict__ s0, u16* __restrict__ d0, long n0,
                                              const float* __restrict__ s1, u16* __restrict__ d1, long n1,
                                              const float* __restrict__ s2, u16* __restrict__ d2, long n2) {
    long i = ((long)blockIdx.x * 256 + threadIdx.x) * 4;
    const float* s; u16* d; long off;
    if (i < n0)           { s = s0; d = d0; off = i; }
    else if (i < n0 + n1) { s = s1; d = d1; off = i - n0; }
    else if (i < n0 + n1 + n2) { s = s2; d = d2; off = i - n0 - n1; }
    else return;
    float4 v = *(const float4*)(s + off);
    uint32_t lo = f2bf(v.x) | ((uint32_t)f2bf(v.y) << 16);
    uint32_t hi = f2bf(v.z) | ((uint32_t)f2bf(v.w) << 16);
    *(uint2*)(d + off) = make_uint2(lo, hi);
}

// ---------------------------------------------------------------- embed + token-normalize (fp32, feeds topk)
__global__ __launch_bounds__(256) void embed_k(const int* __restrict__ ids,
                                               const float* __restrict__ wte,
                                               float* __restrict__ x,
                                               float* __restrict__ xnt) {
    __shared__ float sb[4];
    int tok = blockIdx.x;
    const float* src = wte + (size_t)ids[tok] * cE;
    int t = threadIdx.x;
    float v0 = src[t], v1 = src[t + 256], v2 = src[t + 512];
    float tot = blockReduceSum256(v0 * v0 + v1 * v1 + v2 * v2, sb);
    float inv = 1.0f / (sqrtf(tot) + 1e-8f);
    size_t o = (size_t)tok * cE + t;
    x[o] = v0; x[o + 256] = v1; x[o + 512] = v2;
    xnt[o] = v0 * inv; xnt[o + 256] = v1 * inv; xnt[o + 512] = v2 * inv;
}

// ---------------------------------------------------------------- rmsnorm -> bf16
__global__ __launch_bounds__(256) void rmsnorm_bf_k(const float* __restrict__ in,
                                                    const float* __restrict__ w,
                                                    u16* __restrict__ out) {
    __shared__ float sb[4];
    size_t row = blockIdx.x;
    const float* src = in + row * cE;
    int t = threadIdx.x;
    float v0 = src[t], v1 = src[t + 256], v2 = src[t + 512];
    float tot = blockReduceSum256(v0 * v0 + v1 * v1 + v2 * v2, sb);
    float s = 1.0f / sqrtf(tot * (1.0f / cE) + 1e-10f);
    out[row * cE + t]       = f2bf(v0 * s * w[t]);
    out[row * cE + t + 256] = f2bf(v1 * s * w[t + 256]);
    out[row * cE + t + 512] = f2bf(v2 * s * w[t + 512]);
}

// ---------------------------------------------------------------- inverse row norm of a (bf16 input)
__global__ __launch_bounds__(256) void invna_bf_k(const u16* __restrict__ a,
                                                  float* __restrict__ invna) {
    __shared__ float sb[4];
    size_t row = blockIdx.x;
    const u16* src = a + row * cE;
    int t = threadIdx.x;
    float v0 = bf2f(src[t]), v1 = bf2f(src[t + 256]), v2 = bf2f(src[t + 512]);
    float tot = blockReduceSum256(v0 * v0 + v1 * v1 + v2 * v2, sb);
    if (t == 0) invna[row] = 1.0f / sqrtf(tot + 1e-8f);
}

// ---------------------------------------------------------------- final row extract + rmsnorm(lnf) -> bf16
__global__ __launch_bounds__(256) void final_bf_k(const float* __restrict__ h,
                                                  const float* __restrict__ lnf,
                                                  u16* __restrict__ finn) {
    __shared__ float sb[4];
    int tok = blockIdx.x;
    int b = tok >> 11, tt = tok & 2047;
    int i = tt >> 8, c = tt & 255;
    size_t row = (size_t)(b * cN + i) * cTL + (cTL - cC) + c;
    const float* src = h + row * cE;
    int t = threadIdx.x;
    float v0 = src[t], v1 = src[t + 256], v2 = src[t + 512];
    float tot = blockReduceSum256(v0 * v0 + v1 * v1 + v2 * v2, sb);
    float s = 1.0f / sqrtf(tot * (1.0f / cE) + 1e-10f);
    size_t o = (size_t)tok * cE + t;
    finn[o]       = f2bf(v0 * s * lnf[t]);
    finn[o + 256] = f2bf(v1 * s * lnf[t + 256]);
    finn[o + 512] = f2bf(v2 * s * lnf[t + 512]);
}

// ---------------------------------------------------------------- pair scores v3 (fp32, deterministic; ct split 8)
// Block: 32 A-rows (ct tile) x 256 B-rows; 4 waves, wave-per-64-B-rows; lane: 4 A-rows x 8 B-cols.
__global__ __launch_bounds__(256) void pair_scores_k(const float* __restrict__ xnt,
                                                     float* __restrict__ partial) {
    __shared__ float As[16][32];
    __shared__ float Bs[4][16][64];
    __shared__ float rowmax[4][32];
    int ct = blockIdx.x;
    int p  = blockIdx.y;
    int b = p / 28, pp = p % 28;
    int i = 1; while (pp >= i) { pp -= i; i++; }
    int j = pp;
    const float* Abase = xnt + ((size_t)(b * cT) + i * cC + ct * 32) * cE;
    const float* Bbase = xnt + ((size_t)(b * cT) + j * cC) * cE;
    int tid = threadIdx.x, lane = tid & 63, w = tid >> 6;
    int ly = lane >> 3, lx = lane & 7;
    const float* bw = Bbase + (size_t)(w * 64) * cE;

    float acc[4][8];
    #pragma unroll
    for (int a2 = 0; a2 < 4; a2++)
        #pragma unroll
        for (int b2 = 0; b2 < 8; b2++) acc[a2][b2] = 0.f;

    for (int k0 = 0; k0 < cE; k0 += 16) {
        if (tid < 128) {
            int srow = tid >> 2, skc = (tid & 3) << 2;
            float4 va = *(const float4*)(Abase + (size_t)srow * cE + k0 + skc);
            As[skc + 0][srow] = va.x; As[skc + 1][srow] = va.y;
            As[skc + 2][srow] = va.z; As[skc + 3][srow] = va.w;
        }
        #pragma unroll
        for (int q = 0; q < 4; q++) {
            int id = (q << 6) + lane;
            int br = id >> 2, bkc = (id & 3) << 2;
            float4 vb = *(const float4*)(bw + (size_t)br * cE + k0 + bkc);
            Bs[w][bkc + 0][br] = vb.x; Bs[w][bkc + 1][br] = vb.y;
            Bs[w][bkc + 2][br] = vb.z; Bs[w][bkc + 3][br] = vb.w;
        }
        __syncthreads();
        #pragma unroll
        for (int k = 0; k < 16; k++) {
            float av[4], bv[8];
            *(float4*)&av[0] = *(float4*)&As[k][ly << 2];
            *(float4*)&bv[0] = *(float4*)&Bs[w][k][lx << 3];
            *(float4*)&bv[4] = *(float4*)&Bs[w][k][(lx << 3) + 4];
            #pragma unroll
            for (int r = 0; r < 4; r++)
                #pragma unroll
                for (int q = 0; q < 8; q++)
                    acc[r][q] = fmaf(av[r], bv[q], acc[r][q]);
        }
        __syncthreads();
    }
    #pragma unroll
    for (int r = 0; r < 4; r++) {
        float m = acc[r][0];
        #pragma unroll
        for (int q = 1; q < 8; q++) m = fmaxf(m, acc[r][q]);
        m = fmaxf(m, __shfl_xor(m, 1, 64));
        m = fmaxf(m, __shfl_xor(m, 2, 64));
        m = fmaxf(m, __shfl_xor(m, 4, 64));
        if (lx == 0) rowmax[w][(ly << 2) + r] = m;
    }
    __syncthreads();
    if (tid == 0) {
        float s = 0.f;
        for (int r = 0; r < 32; r++)
            s += fmaxf(fmaxf(rowmax[0][r], rowmax[1][r]),
                       fmaxf(rowmax[2][r], rowmax[3][r]));
        partial[p * 8 + ct] = s;   // fixed order -> deterministic
    }
}

// ---------------------------------------------------------------- top-k + sort + weights
__global__ void score_topk_k(const float* __restrict__ partial,
                             int* __restrict__ sidx, float* __restrict__ sw) {
    __shared__ float sc[2][8][8];
    int t = threadIdx.x;
    if (t < 56) {
        int b = t / 28, pp = t % 28;
        int i = 1; while (pp >= i) { pp -= i; i++; }
        int j = pp;
        float s = 0.f;
        for (int ct = 0; ct < 8; ct++) s += partial[t * 8 + ct];
        sc[b][i][j] = s;
    }
    __syncthreads();
    if (t < 16) {
        int b = t >> 3, i = t & 7;
        int nsel = i < 3 ? i : 3;
        if (nsel > 0) {
            float loc[7];
            for (int j2 = 0; j2 < i; j2++) loc[j2] = sc[b][i][j2];
            int idxs[3]; float vals[3];
            for (int s = 0; s < nsel; s++) {
                int am = 0; float mv = loc[0];
                for (int j2 = 1; j2 < i; j2++) if (loc[j2] > mv) { mv = loc[j2]; am = j2; }
                idxs[s] = am; vals[s] = mv; loc[am] = -1e30f;
            }
            for (int a = 0; a < nsel; a++)
                for (int c2 = a + 1; c2 < nsel; c2++)
                    if (idxs[c2] < idxs[a]) {
                        int ti = idxs[a]; idxs[a] = idxs[c2]; idxs[c2] = ti;
                        float tv = vals[a]; vals[a] = vals[c2]; vals[c2] = tv;
                    }
            float den = vals[0] + 1e-8f;
            for (int s = 0; s < nsel; s++) {
                sidx[(b * 8 + i) * 3 + s] = idxs[s];
                sw[(b * 8 + i) * 3 + s]   = vals[s] / den;
            }
        }
    }
}

// ---------------------------------------------------------------- assemble extended context h (fp32)
__global__ __launch_bounds__(192) void build_k(const float* __restrict__ x,
                                               const int* __restrict__ sidx,
                                               const float* __restrict__ sw,
                                               float* __restrict__ h) {
    int m = blockIdx.x, r = blockIdx.y;
    int b = m >> 3, i = m & 7;
    int nsel = i < 3 ? i : 3;
    int pad = cTL - (nsel + 1) * cC;
    int pos = r - pad;
    float4 val = make_float4(0.f, 0.f, 0.f, 0.f);
    if (pos >= 0) {
        if (pos < nsel * cC) {
            int s = pos >> 8;
            int jj = sidx[(b * 8 + i) * 3 + s];
            float wg = sw[(b * 8 + i) * 3 + s];
            const float4* src = (const float4*)(x + ((size_t)(b * cT) + jj * cC + (pos & 255)) * cE);
            float4 v = src[threadIdx.x];
            val = make_float4(v.x * wg, v.y * wg, v.z * wg, v.w * wg);
        } else {
            int c = pos - nsel * cC;
            const float4* src = (const float4*)(x + ((size_t)(b * cT) + i * cC + c) * cE);
            val = src[threadIdx.x];
        }
    }
    ((float4*)(h + ((size_t)m * cTL + r) * cE))[threadIdx.x] = val;
}

enum { GE_F32 = 0, GE_RELU = 1, GE_CS = 2, GE_ADDH = 3, GE_ANBT = 4 };

// ---------------------------------------------------------------- 256x256 MFMA GEMM: 8-phase schedule, batched
// NT: C[m,n] = sum_k A[z*sA + m*lda + k] * B[z*sB + n*ldb + k]. BK=64, 2-buffer LDS, 8 waves (2Mx4N).
// swz: 3 = XCD owns m-chunk, sweeps n; 4 = XCD owns n-chunk, sweeps m fastest (for small-A GEMMs).
// kcap: Keff = min(K, n0+256) (tril consumer). GE_CS: skip n0>m0 tiles (never read downstream).
template <int EPI>
__global__ __launch_bounds__(512, 2) void gemm256(
        const u16* __restrict__ A, int lda, size_t sA,
        const u16* __restrict__ B, int ldb, size_t sB,
        void* __restrict__ Cv, int ldc, size_t sC, int K,
        const float* __restrict__ bias,
        u16* __restrict__ p0, u16* __restrict__ p1, u16* __restrict__ p2,
        const float* __restrict__ invn, const float* __restrict__ sp,
        int swz, int kcap)
{
    __shared__ __align__(16) u16 lds[65536];   // 2 buffers x {A:16384, B:16384} u16 (128 KB)
    int bx = blockIdx.x, by = blockIdx.y;
    const int z = blockIdx.z;
    if (swz == 3) {   // XCD owns gy/8 m-tiles; all XCDs sweep n in sync
        int gx = gridDim.x, gy = gridDim.y;
        int orig = by * gx + bx;
        int mpx = gy >> 3;
        int xcd = orig & 7, idx = orig >> 3;
        by = xcd * mpx + idx % mpx;
        bx = idx / mpx;
        (void)gx;
    } else if (swz == 4) {   // XCD owns contiguous n-chunk, sweeps m fastest (nwg%8==0)
        int gx = gridDim.x, gy = gridDim.y;
        int nwg = gx * gy;
        int orig = by * gx + bx;
        int wg = (orig & 7) * (nwg >> 3) + (orig >> 3);
        by = wg % gy;
        bx = wg / gy;
    }
    const int n0 = bx << 8, m0 = by << 8;
    const int tid = threadIdx.x, lane = tid & 63, w = tid >> 6;
    const int wm = w >> 2, wn = w & 3;

    if constexpr (EPI == GE_CS) {
        if (n0 > m0) return;   // strictly-upper 256-tile: never read (K-capped consumer)
    }

    const int Keff = kcap ? ((K < n0 + 256) ? K : n0 + 256) : K;
    const int NT = Keff >> 6;

    const u16* Ab = A + z * sA + (size_t)m0 * lda;
    const u16* Bb = B + z * sB + (size_t)n0 * ldb;

    // staging: half-tile = 128 rows x 64 u16 (16KB); thread covers rows tid>>3 and +64, chunk tid&7
    const int srow0 = tid >> 3;                        // 0..63
    const int sq    = (tid & 7) ^ (srow0 & 7);         // pre-swizzled global 16B-chunk

    auto STAGE = [&](int kt, int op, int half) {       // op: 0=A, 1=B
        const u16* base = op ? Bb : Ab;
        const int  ld   = op ? ldb : lda;
        const u16* src = base + (size_t)(half * 128 + srow0) * ld + (size_t)kt * 64 + sq * 8;
        u16* d = lds + ((kt & 1) << 15) + (op << 14) + (half << 13) + tid * 8;
        GLOAD16(src, d);
        GLOAD16(src + (size_t)64 * ld, d + 4096);
    };

    f32x4 acc[8][4];
    #pragma unroll
    for (int m = 0; m < 8; m++)
        #pragma unroll
        for (int n = 0; n < 4; n++) acc[m][n] = (f32x4){0.f, 0.f, 0.f, 0.f};

    const int l15 = lane & 15;
    const int klo = lane >> 4;                          // 0..3
    const int arow = (l15) * 64;                        // + mf*1024
    const int brow = ((wn & 1) * 64 + l15) * 64;        // + nf*1024
    const int abase = (wm << 13);
    const int bbase = 16384 + ((wn >> 1) << 13);

    // prologue: tile0 all 4 halves + tile1 B halves; wait tile0 (4 stay in flight)
    STAGE(0, 0, 0); STAGE(0, 0, 1); STAGE(0, 1, 0); STAGE(0, 1, 1);
    if (NT > 1) { STAGE(1, 1, 0); STAGE(1, 1, 1); }
    asm volatile("s_waitcnt vmcnt(4)" ::: "memory");
    BARRIER();

    for (int kt = 0; kt < NT; ++kt) {
        const int buf = (kt & 1) << 15;
        bf16x8 a0[4], a1[4], bf0[4], bf1[4];
        // ---- phase 0: B kk0 (4) + A m0-3 kk0 (4); stage (kt+1, A0)
        #pragma unroll
        for (int nf = 0; nf < 4; nf++)
            bf0[nf] = *(const bf16x8*)(lds + buf + bbase + brow + nf * 1024 + (((klo) ^ (l15 & 7)) << 3));
        #pragma unroll
        for (int mf = 0; mf < 4; mf++)
            a0[mf] = *(const bf16x8*)(lds + buf + abase + arow + mf * 1024 + (((klo) ^ (l15 & 7)) << 3));
        if (kt + 1 < NT) STAGE(kt + 1, 0, 0);
        BARRIER();
        __builtin_amdgcn_s_setprio(1);
        #pragma unroll
        for (int mf = 0; mf < 4; mf++)
            #pragma unroll
            for (int nf = 0; nf < 4; nf++)
                acc[mf][nf] = __builtin_amdgcn_mfma_f32_16x16x32_bf16(a0[mf], bf0[nf], acc[mf][nf], 0, 0, 0);
        __builtin_amdgcn_s_setprio(0);
        BARRIER();
        // ---- phase 1: A m4-7 kk0 (4); stage (kt+1, A1)
        #pragma unroll
        for (int mf = 0; mf < 4; mf++)
            a1[mf] = *(const bf16x8*)(lds + buf + abase + arow + (mf + 4) * 1024 + (((klo) ^ (l15 & 7)) << 3));
        if (kt + 1 < NT) STAGE(kt + 1, 0, 1);
        BARRIER();
        __builtin_amdgcn_s_setprio(1);
        #pragma unroll
        for (int mf = 0; mf < 4; mf++)
            #pragma unroll
            for (int nf = 0; nf < 4; nf++)
                acc[mf + 4][nf] = __builtin_amdgcn_mfma_f32_16x16x32_bf16(a1[mf], bf0[nf], acc[mf + 4][nf], 0, 0, 0);
        __builtin_amdgcn_s_setprio(0);
        BARRIER();
        // ---- phase 2: B kk1 (4) + A m0-3 kk1 (4); no stage
        #pragma unroll
        for (int nf = 0; nf < 4; nf++)
            bf1[nf] = *(const bf16x8*)(lds + buf + bbase + brow + nf * 1024 + (((4 + klo) ^ (l15 & 7)) << 3));
        #pragma unroll
        for (int mf = 0; mf < 4; mf++)
            a0[mf] = *(const bf16x8*)(lds + buf + abase + arow + mf * 1024 + (((4 + klo) ^ (l15 & 7)) << 3));
        BARRIER();
        __builtin_amdgcn_s_setprio(1);
        #pragma unroll
        for (int mf = 0; mf < 4; mf++)
            #pragma unroll
            for (int nf = 0; nf < 4; nf++)
                acc[mf][nf] = __builtin_amdgcn_mfma_f32_16x16x32_bf16(a0[mf], bf1[nf], acc[mf][nf], 0, 0, 0);
        __builtin_amdgcn_s_setprio(0);
        BARRIER();
        // ---- phase 3: A m4-7 kk1 (4); stage (kt+2, B0)+(kt+2, B1); vmcnt(4)
        #pragma unroll
        for (int mf = 0; mf < 4; mf++)
            a1[mf] = *(const bf16x8*)(lds + buf + abase + arow + (mf + 4) * 1024 + (((4 + klo) ^ (l15 & 7)) << 3));
        if (kt + 2 < NT) {
            STAGE(kt + 2, 1, 0); STAGE(kt + 2, 1, 1);
            asm volatile("s_waitcnt vmcnt(4)" ::: "memory");
        } else if (kt + 1 < NT) {
            asm volatile("s_waitcnt vmcnt(0)" ::: "memory");
        }
        BARRIER();
        __builtin_amdgcn_s_setprio(1);
        #pragma unroll
        for (int mf = 0; mf < 4; mf++)
            #pragma unroll
            for (int nf = 0; nf < 4; nf++)
                acc[mf + 4][nf] = __builtin_amdgcn_mfma_f32_16x16x32_bf16(a1[mf], bf1[nf], acc[mf + 4][nf], 0, 0, 0);
        __builtin_amdgcn_s_setprio(0);
        BARRIER();
    }

    // epilogue: C/D layout col=lane&15, row=(lane>>4)*4+j
    const int r0 = (lane >> 4) << 2;
    const int c0 = lane & 15;

    if constexpr (EPI == GE_F32) {
        float* Cb = (float*)Cv;
        #pragma unroll
        for (int mf = 0; mf < 8; mf++) {
            int gmb = m0 + (wm << 7) + (mf << 4) + r0;
            #pragma unroll
            for (int j = 0; j < 4; j++) {
                float* crow = Cb + (size_t)(gmb + j) * ldc;
                #pragma unroll
                for (int nf = 0; nf < 4; nf++)
                    crow[n0 + (wn << 6) + (nf << 4) + c0] = acc[mf][nf][j];
            }
        }
    } else if constexpr (EPI == GE_ADDH) {
        float* Cb = (float*)Cv;
        #pragma unroll
        for (int mf = 0; mf < 8; mf++) {
            int gmb = m0 + (wm << 7) + (mf << 4) + r0;
            #pragma unroll
            for (int j = 0; j < 4; j++) {
                float* crow = Cb + (size_t)(gmb + j) * ldc;
                #pragma unroll
                for (int nf = 0; nf < 4; nf++) {
                    int gn = n0 + (wn << 6) + (nf << 4) + c0;
                    crow[gn] = crow[gn] + acc[mf][nf][j] + bias[gn];
                }
            }
        }
    } else if constexpr (EPI == GE_RELU) {
        const bool aregion = (n0 < cE);
        #pragma unroll
        for (int mf = 0; mf < 8; mf++) {
            const int gmb = m0 + (wm << 7) + (mf << 4) + r0;
            const int zz = gmb >> 10, cm = gmb & 1023;
            #pragma unroll
            for (int nf = 0; nf < 4; nf++) {
                const int gn = n0 + (wn << 6) + (nf << 4) + c0;
                const float bv = bias[gn];
                u16 rb[4];
                #pragma unroll
                for (int j = 0; j < 4; j++) {
                    float tv = acc[mf][nf][j] + bv;
                    tv = fmaxf(tv, 0.f);
                    rb[j] = f2bf(tv * tv);
                }
                if (aregion) {
                    #pragma unroll
                    for (int j = 0; j < 4; j++)
                        p0[(size_t)(gmb + j) * cE + gn] = rb[j];
                    uint32_t lo = rb[0] | ((uint32_t)rb[1] << 16);
                    uint32_t hi = rb[2] | ((uint32_t)rb[3] << 16);
                    *(uint2*)&p1[(size_t)zz * (cE * cTL) + (size_t)gn * cTL + cm] = make_uint2(lo, hi);
                } else {
                    #pragma unroll
                    for (int j = 0; j < 4; j++)
                        p2[(size_t)(gmb + j) * cPIN + (gn - cE)] = rb[j];
                }
            }
        }
    } else if constexpr (EPI == GE_CS) {
        u16* Cb = (u16*)Cv + z * sC;
        const float* invz = invn + (z << 10);
        float inn[4];
        #pragma unroll
        for (int nf = 0; nf < 4; nf++)
            inn[nf] = invz[n0 + (wn << 6) + (nf << 4) + c0];
        #pragma unroll
        for (int mf = 0; mf < 8; mf++) {
            int gmb = m0 + (wm << 7) + (mf << 4) + r0;
            #pragma unroll
            for (int j = 0; j < 4; j++) {
                int gm = gmb + j;
                float im = invz[gm];
                const float* spr = sp + (size_t)gm * cTL;
                u16* crow = Cb + (size_t)gm * ldc;
                #pragma unroll
                for (int nf = 0; nf < 4; nf++) {
                    int gn = n0 + (wn << 6) + (nf << 4) + c0;
                    float v = (gn <= gm) ? acc[mf][nf][j] * im * inn[nf] * spr[gn] : 0.f;
                    crow[gn] = f2bf(v);
                }
            }
        }
    } else if constexpr (EPI == GE_ANBT) {
        // acc = a_newT tile: e = m0 + wm*128 + mf*16 + r0 + j, m = n0 + wn*64 + nf*16 + c0
        // Fused: fi[z*TL + m][e] *= a_new; transpose through LDS in 2 e-chunks of 128.
        u16 (*tr)[136] = (u16(*)[136])lds;   // 256(m) x 136(e) u16 = 69.6 KB of 128 KB
        #pragma unroll
        for (int ch = 0; ch < 2; ch++) {
            asm volatile("s_waitcnt lgkmcnt(0)" ::: "memory");
            BARRIER();                        // pipeline LDS / previous chunk fully read
            if (wm == ch) {
                #pragma unroll
                for (int mf = 0; mf < 8; mf++) {
                    const int el = (mf << 4) + r0;              // 0..127 within chunk
                    #pragma unroll
                    for (int nf = 0; nf < 4; nf++) {
                        const int ml = (wn << 6) + (nf << 4) + c0;   // 0..255
                        u16 t0 = f2bf(acc[mf][nf][0]), t1 = f2bf(acc[mf][nf][1]);
                        u16 t2 = f2bf(acc[mf][nf][2]), t3 = f2bf(acc[mf][nf][3]);
                        *(uint2*)&tr[ml][el] = make_uint2(t0 | ((uint32_t)t1 << 16),
                                                          t2 | ((uint32_t)t3 << 16));
                    }
                }
            }
            asm volatile("s_waitcnt lgkmcnt(0)" ::: "memory");
            BARRIER();
            const int ebase = m0 + (ch << 7);
            #pragma unroll
            for (int it = 0; it < 8; it++) {
                int idx = (it << 9) + tid;        // 4096 slots = 256 m x 16 e-groups
                int mrow = idx >> 4, eg = (idx & 15) << 3;
                u16* fr = p0 + ((size_t)(z * cTL + n0 + mrow)) * cPIN + ebase + eg;
                uint4 fv = *(uint4*)fr;
                u16* pf = (u16*)&fv;
                u16 res[8];
                #pragma unroll
                for (int q = 0; q < 8; q++)
                    res[q] = f2bf(bf2f(tr[mrow][eg + q]) * bf2f(pf[q]));
                *(uint4*)fr = *(uint4*)res;
            }
        }
    }
}

// ---------------------------------------------------------------- launch
extern "C" void kernel_launch(void* const* d_in, const int* in_sizes, int n_in,
                              void* d_out, int out_size, void* d_ws, size_t ws_size,
                              hipStream_t stream) {
    const int*   ids  = (const int*)d_in[0];
    const float* wte  = (const float*)d_in[1];
    const float* rmsw = (const float*)d_in[2];
    const float* enrw = (const float*)d_in[3];
    const float* enrb = (const float*)d_in[4];
    const float* sp   = (const float*)d_in[5];
    const float* fusw = (const float*)d_in[6];
    const float* fusb = (const float*)d_in[7];
    const float* lnfw = (const float*)d_in[8];
    float* out = (float*)d_out;

    // fp32 workspace
    float* ws   = (float*)d_ws;
    float* x    = ws;                      // 3,145,728
    float* xnt  = x    + 3145728;          // 3,145,728
    float* h    = xnt  + 3145728;          // 12,582,912
    float* invn = h    + 12582912;         // 16,384
    float* part = invn + 16384;            // 512
    float* swv  = part + 512;              // 64
    int*   sidx = (int*)(swv + 64);        // 64
    // bf16 workspace
    u16* wteb  = (u16*)(sidx + 64);        // 24,576,000
    u16* enrwb = wteb  + 24576000;         //  9,437,184
    u16* fuswb = enrwb + 9437184;          //  7,077,888
    u16* xnb   = fuswb + 7077888;          // 12,582,912 (reused as finn bf16)
    u16* abuf  = xnb   + 12582912;         // 12,582,912
    u16* aTb   = abuf  + 12582912;         // 12,582,912
    u16* fi    = aTb   + 12582912;         // 37,748,736
    u16* csb   = fi    + 37748736;         // 16,777,216
    u16* finnb = xnb;

    // 0. weight conversion fp32->bf16 (single launch)
    cvt3_k<<<(24576000 + 9437184 + 7077888) / 1024, 256, 0, stream>>>(
        wte, wteb, 24576000, enrw, enrwb, 9437184, fusw, fuswb, 7077888);

    // 1. embed + token normalize (fp32)
    embed_k<<<cB * cT, 256, 0, stream>>>(ids, wte, x, xnt);
    // 2. retrieval scores + top-k + assembly (fp32, deterministic)
    pair_scores_k<<<dim3(8, 56), 256, 0, stream>>>(xnt, part);
    score_topk_k<<<1, 64, 0, stream>>>(part, sidx, swv);
    build_k<<<dim3(cNCH, cTL), 192, 0, stream>>>(x, sidx, swv, h);

    // 3. layers
    for (int l = 0; l < cL; l++) {
        rmsnorm_bf_k<<<cMR, 256, 0, stream>>>(h, rmsw + (size_t)l * cE, xnb);
        // xp = relu(xn @ enr_w.T + b)^2 ; writes a (row-major + transposed) and b/x1 into fi
        gemm256<GE_RELU><<<dim3(cED / 256, cMR / 256, 1), 512, 0, stream>>>(
            xnb, cE, 0, enrwb + (size_t)l * cED * cE, cE, 0,
            nullptr, 0, 0, cE, enrb + (size_t)l * cED,
            abuf, aTb, fi, nullptr, nullptr, 3, 0);
        invna_bf_k<<<cMR, 256, 0, stream>>>(abuf, invn);
        // M = tril(sp) * cosine(a,a)   (batched 256-tile; upper tiles skipped)
        gemm256<GE_CS><<<dim3(4, 4, cNCH), 512, 0, stream>>>(
            abuf, cE, (size_t)cTL * cE, abuf, cE, (size_t)cTL * cE,
            csb, cTL, (size_t)cTL * cTL, cE, nullptr,
            nullptr, nullptr, nullptr, invn, sp + (size_t)l * cTL * cTL, 0, 0);
        // a_newT[e][m] = sum_c aT[e][c]*M[m][c] (K capped at n0+256); fused fi[m][e] *= result
        gemm256<GE_ANBT><<<dim3(4, 3, cNCH), 512, 0, stream>>>(
            aTb, cTL, (size_t)cE * cTL, csb, cTL, (size_t)cTL * cTL,
            nullptr, 0, 0, cTL, nullptr,
            fi, nullptr, nullptr, nullptr, nullptr, 0, 1);
        // h += fi @ fus_w.T + fus_b
        gemm256<GE_ADDH><<<dim3(cE / 256, cMR / 256, 1), 512, 0, stream>>>(
            fi, cPIN, 0, fuswb + (size_t)l * cE * cPIN, cPIN, 0,
            h, cE, 0, cPIN, fusb + (size_t)l * cE,
            nullptr, nullptr, nullptr, nullptr, nullptr, 3, 0);
    }

    // 4. final norm + logits (A = finnb is only 6 MB -> n-chunked XCD map, m-fastest sweep)
    final_bf_k<<<cB * cT, 256, 0, stream>>>(h, lnfw, finnb);
    gemm256<GE_F32><<<dim3(cV / 256, (cB * cT) / 256, 1), 512, 0, stream>>>(
        finnb, cE, 0, wteb, cE, 0, out, cV, 0, cE,
        nullptr, nullptr, nullptr, nullptr, nullptr, nullptr, 4, 0);
}